// Round 14
// baseline (1362.055 us; speedup 1.0000x reference)
//
#include <hip/hip_runtime.h>
#include <hip/hip_bf16.h>
#include <math.h>

#ifndef M_PI
#define M_PI 3.14159265358979323846
#endif

#define B_    1024
#define SX    180
#define SY    130
#define NC    3
#define IMG   23400
#define FLATK 70200
#define KPAD  70208
#define HID1  2808
#define NOUT  180
#define XROW  131
#define H1STR 2816
#define KSTEPS 2194   // KPAD/32
#define KCH    549    // ceil(KSTEPS/4)
#define NKZ    4
#define WTHIRD 936    // HID1/3 W-rows converted per spectral kernel

typedef __attribute__((ext_vector_type(8))) short short8;
typedef __attribute__((ext_vector_type(4))) float f32x4;
typedef __attribute__((address_space(3))) unsigned int lds_u32;
typedef __attribute__((address_space(1))) const unsigned int glb_u32;

// table sizes (shorts), padded so fragment reads stay in-bounds
#define TY_SH   5632
#define TX_SH   12800
#define TXI_SH  13824
#define TIY_SH  6144

__device__ __forceinline__ unsigned short f2bf(float f){
  __hip_bfloat16 h = __float2bfloat16(f);
  return __builtin_bit_cast(unsigned short, h);
}
__device__ __forceinline__ float bf2f(unsigned short u){
  __hip_bfloat16 h = __builtin_bit_cast(__hip_bfloat16, u);
  return __bfloat162float(h);
}
__device__ __forceinline__ void split_bf(float f, unsigned short &hi, unsigned short &lo){
  hi = f2bf(f);
  lo = f2bf(f - bf2f(hi));
}
__device__ __forceinline__ void gl_lds16(const void* g, void* l){
  __builtin_amdgcn_global_load_lds((glb_u32*)g, (lds_u32*)l, 16, 0, 0);
}
__device__ __forceinline__ float gelu_f(float v){
  return 0.5f * v * (1.0f + erff(v * 0.70710678118654752f));
}
__device__ __forceinline__ short8 ld_g8(const unsigned short* p){
  return *(const short8*)p;
}

// ---- W-row fp32->bf16 convert (one row per block; coalesced) ----
__device__ __forceinline__ void cvt_w_row(const float* __restrict__ W,
                                          unsigned short* __restrict__ Wbf, int row){
  int t = threadIdx.x;
  const float* src = W + (size_t)row*FLATK;
  unsigned short* dst = Wbf + (size_t)row*KPAD;
  for (int gi = t; gi < KPAD/8; gi += 256){
    if (gi*8 >= FLATK){
      *(ushort4*)(dst + gi*8)     = make_ushort4(0,0,0,0);
      *(ushort4*)(dst + gi*8 + 4) = make_ushort4(0,0,0,0);
    } else {
      float4 v0 = *(const float4*)(src + gi*8);
      float4 v1 = *(const float4*)(src + gi*8 + 4);
      ushort4 u0, u1;
      u0.x=f2bf(v0.x); u0.y=f2bf(v0.y); u0.z=f2bf(v0.z); u0.w=f2bf(v0.w);
      u1.x=f2bf(v1.x); u1.y=f2bf(v1.y); u1.z=f2bf(v1.z); u1.w=f2bf(v1.w);
      *(ushort4*)(dst + gi*8)     = u0;
      *(ushort4*)(dst + gi*8 + 4) = u1;
    }
  }
}

// ================= tables (split hi/lo bf16, padded) =================
__global__ void k_tables2(unsigned short* __restrict__ TyH, unsigned short* __restrict__ TyL,
                          unsigned short* __restrict__ TxH, unsigned short* __restrict__ TxL,
                          unsigned short* __restrict__ TxiH, unsigned short* __restrict__ TxiL,
                          unsigned short* __restrict__ TiyH, unsigned short* __restrict__ TiyL){
  int i = blockIdx.x*256 + threadIdx.x;
  unsigned short h, l;
  if (i < TY_SH){
    int m = i/168, y = i%168;
    float v = 0.f;
    if (m < 32 && y < SY){
      int ky = m>>1, ri = m&1;
      double ang = 2.0*M_PI*(double)((ky*y)%SY)/(double)SY;
      v = ri ? (float)(-sin(ang)) : (float)cos(ang);
    }
    split_bf(v,h,l); TyH[i]=h; TyL[i]=l;
  }
  if (i < TX_SH){
    int n = i/200, x = i%200;
    float v = 0.f;
    if (x < SX){
      int kxi = n>>1, ri = n&1;
      int kx = (kxi<16)? kxi : kxi+148;
      double ang = 2.0*M_PI*(double)((kx*x)%SX)/(double)SX;
      v = ri ? (float)sin(ang) : (float)cos(ang);
    }
    split_bf(v,h,l); TxH[i]=h; TxL[i]=l;
  }
  if (i < TXI_SH){
    int x = i/72, k = i%72;
    float v = 0.f;
    if (x < SX && k < 64){
      int kxi = k>>1, ri = k&1;
      int kx = (kxi<16)? kxi : kxi+148;
      double ang = 2.0*M_PI*(double)((kx*x)%SX)/(double)SX;
      v = (float)((ri ? sin(ang) : cos(ang)) / (double)SX);
    }
    split_bf(v,h,l); TxiH[i]=h; TxiL[i]=l;
  }
  if (i < TIY_SH){
    int y = i/40, m = i%40;
    float v = 0.f;
    if (y < SY && m < 32){
      int ky = m>>1, ri = m&1;
      if (m == 0) v = 1.0f/(float)SY;
      else if (m == 1) v = 0.f;
      else {
        double ang = 2.0*M_PI*(double)((ky*y)%SY)/(double)SY;
        v = (float)((ri ? -2.0*sin(ang) : 2.0*cos(ang)) / (double)SY);
      }
    }
    split_bf(v,h,l); TiyH[i]=h; TiyL[i]=l;
  }
}

// ================= layer-1 fwd (cvt rows [0,936) interleaved 1:1) =================
__global__ __launch_bounds__(256) void k_fwd0(const float* __restrict__ xin,
                                              const unsigned short* __restrict__ TyH,
                                              const unsigned short* __restrict__ TyL,
                                              const unsigned short* __restrict__ TxH,
                                              const unsigned short* __restrict__ TxL,
                                              float* __restrict__ U1,
                                              float* __restrict__ Ug,
                                              const float* __restrict__ Wsrc,
                                              unsigned short* __restrict__ Wbf){
  int i = blockIdx.x;
  int bid;
  if (i < 1872){
    if (i & 1){ cvt_w_row(Wsrc, Wbf, i >> 1); return; }
    bid = i >> 1;
  } else {
    bid = i - WTHIRD;
  }
  constexpr int DHI = 0;
  constexpr int YTH = 0, YTL = 6400;
  __shared__ unsigned short LB[32256];
  __shared__ float sred[2][4];
  __shared__ float mb[2];
  int t = threadIdx.x, lane = t&63, wv = t>>6, lr = lane&15, lq = lane>>4;

  float s = 0.f, ss = 0.f;
  for (int ii=t; ii<7680; ii+=256){
    int row = ii/40, c4 = (ii - row*40)*4;
    float v[4];
    #pragma unroll
    for (int j=0;j<4;j++){
      int y = c4 + j;
      float val = 0.f;
      if (row < SX && y < SY){
        if (bid < B_)       val = xin[(size_t)bid*(SX*XROW) + row*XROW + y];
        else if (bid == B_) val = (float)row * (1.0f/179.0f);
        else                val = (float)y * (1.0f/129.0f);
      }
      s += val; ss += val*val;
      v[j] = val;
    }
    ushort4 u; u.x=f2bf(v[0]); u.y=f2bf(v[1]); u.z=f2bf(v[2]); u.w=f2bf(v[3]);
    *(ushort4*)&LB[DHI + row*168 + c4] = u;
  }
  for (int o = 32; o >= 1; o >>= 1){ s += __shfl_down(s,o); ss += __shfl_down(ss,o); }
  if (lane == 0){ sred[0][wv] = s; sred[1][wv] = ss; }
  __syncthreads();
  if (t == 0){
    float S = sred[0][0]+sred[0][1]+sred[0][2]+sred[0][3];
    float SS = sred[1][0]+sred[1][1]+sred[1][2]+sred[1][3];
    float mean = S * (1.0f/IMG);
    float var  = SS * (1.0f/IMG) - mean*mean;
    mb[0] = mean; mb[1] = rsqrtf(var + 1e-5f);
  }
  __syncthreads();

  f32x4 acc[2][3] = {};
  #pragma unroll
  for (int ks=0; ks<5; ks++){
    short8 tyh[2], tyl[2];
    #pragma unroll
    for (int mt=0; mt<2; mt++){
      tyh[mt] = ld_g8(&TyH[(mt*16+lr)*168 + ks*32 + lq*8]);
      tyl[mt] = ld_g8(&TyL[(mt*16+lr)*168 + ks*32 + lq*8]);
    }
    #pragma unroll
    for (int j=0; j<3; j++){
      int xr = (wv*3 + j)*16 + lr;
      short8 dh = *(const short8*)&LB[DHI + xr*168 + ks*32 + lq*8];
      #pragma unroll
      for (int mt=0; mt<2; mt++){
        acc[mt][j] = __builtin_amdgcn_mfma_f32_16x16x32_bf16(tyh[mt], dh, acc[mt][j], 0,0,0);
        acc[mt][j] = __builtin_amdgcn_mfma_f32_16x16x32_bf16(tyl[mt], dh, acc[mt][j], 0,0,0);
      }
    }
  }
  __syncthreads();

  {
    float mean = mb[0], istd = mb[1];
    #pragma unroll
    for (int mt=0; mt<2; mt++){
      #pragma unroll
      for (int j=0; j<3; j++){
        int xr = (wv*3 + j)*16 + lr;
        #pragma unroll
        for (int r=0; r<4; r++){
          int m = mt*16 + lq*4 + r;
          float v = acc[mt][j][r];
          if (m == 0) v -= 130.0f*mean;
          v *= istd;
          unsigned short h,l; split_bf(v,h,l);
          LB[YTH + m*200 + xr] = h;
          LB[YTL + m*200 + xr] = l;
        }
      }
    }
  }
  __syncthreads();

  f32x4 acc2[2] = {};
  #pragma unroll
  for (int ks=0; ks<6; ks++){
    short8 txh = ld_g8(&TxH[(wv*16+lr)*200 + ks*32 + lq*8]);
    short8 txl = ld_g8(&TxL[(wv*16+lr)*200 + ks*32 + lq*8]);
    #pragma unroll
    for (int mt=0; mt<2; mt++){
      short8 yh = *(const short8*)&LB[YTH + (mt*16+lr)*200 + ks*32 + lq*8];
      short8 yl = *(const short8*)&LB[YTL + (mt*16+lr)*200 + ks*32 + lq*8];
      acc2[mt] = __builtin_amdgcn_mfma_f32_16x16x32_bf16(yh, txh, acc2[mt], 0,0,0);
      acc2[mt] = __builtin_amdgcn_mfma_f32_16x16x32_bf16(yl, txh, acc2[mt], 0,0,0);
      acc2[mt] = __builtin_amdgcn_mfma_f32_16x16x32_bf16(yh, txl, acc2[mt], 0,0,0);
    }
  }
  float* Ub = (bid < B_) ? (U1 + (size_t)bid*2048) : (Ug + (size_t)(bid - B_)*2048);
  #pragma unroll
  for (int mt=0; mt<2; mt++){
    #pragma unroll
    for (int r=0; r<4; r++){
      int m = mt*16 + lq*4 + r;
      int n = wv*16 + lr;
      Ub[m*64 + n] = acc2[mt][r];
    }
  }
}

// ================= k_mid (cvt rows [936,1872) interleaved 3:1) =================
__global__ __launch_bounds__(256) void k_mid(const float* __restrict__ U1,
                                             const float* __restrict__ Ug,
                                             const float* __restrict__ w1,
                                             const float* __restrict__ w2,
                                             const unsigned short* __restrict__ TxiH,
                                             const unsigned short* __restrict__ TxiL,
                                             const unsigned short* __restrict__ TiyH,
                                             const unsigned short* __restrict__ TiyL,
                                             const unsigned short* __restrict__ TyH,
                                             const unsigned short* __restrict__ TyL,
                                             const unsigned short* __restrict__ TxH,
                                             const unsigned short* __restrict__ TxL,
                                             float* __restrict__ U2,
                                             const float* __restrict__ Wsrc,
                                             unsigned short* __restrict__ Wbf){
  int i = blockIdx.x;
  int bid;
  if (i < 3744){
    if ((i & 3) == 3){ cvt_w_row(Wsrc, Wbf, WTHIRD + (i >> 2)); return; }
    bid = i - (i >> 2);
  } else {
    bid = i - WTHIRD;
  }
  constexpr int ZFH = 0, ZFL = 2304, GH = 4608, GL = 12288;
  constexpr int DAT = 0;
  constexpr int YTH = 0, YTL = 6400;
  __shared__ unsigned short LB[32256];
  __shared__ float sred[2][4];
  __shared__ float mb[2];
  int t = threadIdx.x, lane = t&63, wv = t>>6, lr = lane&15, lq = lane>>4;
  int b = bid/3, o = bid - b*3;

  #pragma unroll
  for (int pp=0; pp<2; pp++){
    int p = t + pp*256;
    int kxi = p & 31, ky = p >> 5;
    const float* w = (kxi < 16) ? w1 : w2;
    int kxm = kxi & 15;
    float ar = 0.f, ai = 0.f;
    #pragma unroll
    for (int ci=0; ci<3; ci++){
      const float* Ui = (ci==0) ? (U1 + (size_t)b*2048) : (Ug + (size_t)(ci-1)*2048);
      float P = Ui[(2*ky  )*64 + 2*kxi  ];
      float Q = Ui[(2*ky  )*64 + 2*kxi+1];
      float R = Ui[(2*ky+1)*64 + 2*kxi  ];
      float S = Ui[(2*ky+1)*64 + 2*kxi+1];
      float zr = P + S, zi = R - Q;
      size_t wo = ((((size_t)ci*3 + o)*16 + kxm)*16 + ky)*2;
      float wr = w[wo], wi = w[wo+1];
      ar += zr*wr - zi*wi;
      ai += zr*wi + zi*wr;
    }
    unsigned short hr,lr_, hi,li, hn,ln;
    split_bf(ar,hr,lr_); split_bf(ai,hi,li); split_bf(-ai,hn,ln);
    LB[ZFH + (2*ky  )*72 + 2*kxi  ] = hr;  LB[ZFL + (2*ky  )*72 + 2*kxi  ] = lr_;
    LB[ZFH + (2*ky  )*72 + 2*kxi+1] = hn;  LB[ZFL + (2*ky  )*72 + 2*kxi+1] = ln;
    LB[ZFH + (2*ky+1)*72 + 2*kxi  ] = hi;  LB[ZFL + (2*ky+1)*72 + 2*kxi  ] = li;
    LB[ZFH + (2*ky+1)*72 + 2*kxi+1] = hr;  LB[ZFL + (2*ky+1)*72 + 2*kxi+1] = lr_;
  }
  __syncthreads();

  f32x4 acc1[2][3] = {};
  #pragma unroll
  for (int ks=0; ks<2; ks++){
    short8 zh[2], zl[2];
    #pragma unroll
    for (int mt=0; mt<2; mt++){
      zh[mt] = *(const short8*)&LB[ZFH + (mt*16+lr)*72 + ks*32 + lq*8];
      zl[mt] = *(const short8*)&LB[ZFL + (mt*16+lr)*72 + ks*32 + lq*8];
    }
    #pragma unroll
    for (int j=0; j<3; j++){
      int x = (wv*3 + j)*16 + lr;
      short8 txh = ld_g8(&TxiH[x*72 + ks*32 + lq*8]);
      short8 txl = ld_g8(&TxiL[x*72 + ks*32 + lq*8]);
      #pragma unroll
      for (int mt=0; mt<2; mt++){
        acc1[mt][j] = __builtin_amdgcn_mfma_f32_16x16x32_bf16(zh[mt], txh, acc1[mt][j], 0,0,0);
        acc1[mt][j] = __builtin_amdgcn_mfma_f32_16x16x32_bf16(zl[mt], txh, acc1[mt][j], 0,0,0);
        acc1[mt][j] = __builtin_amdgcn_mfma_f32_16x16x32_bf16(zh[mt], txl, acc1[mt][j], 0,0,0);
      }
    }
  }
  #pragma unroll
  for (int mt=0; mt<2; mt++){
    #pragma unroll
    for (int j=0; j<3; j++){
      int x = (wv*3 + j)*16 + lr;
      #pragma unroll
      for (int r=0; r<4; r++){
        int m = mt*16 + lq*4 + r;
        unsigned short h,l; split_bf(acc1[mt][j][r], h, l);
        LB[GH + x*40 + m] = h;
        LB[GL + x*40 + m] = l;
      }
    }
  }
  __syncthreads();

  f32x4 acc2[3][9] = {};
  #pragma unroll
  for (int ii=0; ii<3; ii++){
    int x = (wv*3 + ii)*16 + lr;
    short8 gh = *(const short8*)&LB[GH + x*40 + lq*8];
    short8 gl = *(const short8*)&LB[GL + x*40 + lq*8];
    #pragma unroll
    for (int yt=0; yt<9; yt++){
      short8 tyh = ld_g8(&TiyH[(yt*16+lr)*40 + lq*8]);
      short8 tyl = ld_g8(&TiyL[(yt*16+lr)*40 + lq*8]);
      acc2[ii][yt] = __builtin_amdgcn_mfma_f32_16x16x32_bf16(gh, tyh, acc2[ii][yt], 0,0,0);
      acc2[ii][yt] = __builtin_amdgcn_mfma_f32_16x16x32_bf16(gl, tyh, acc2[ii][yt], 0,0,0);
      acc2[ii][yt] = __builtin_amdgcn_mfma_f32_16x16x32_bf16(gh, tyl, acc2[ii][yt], 0,0,0);
    }
  }

  float s = 0.f, ss = 0.f;
  #pragma unroll
  for (int ii=0; ii<3; ii++){
    int xt = wv*3 + ii;
    #pragma unroll
    for (int yt=0; yt<9; yt++){
      #pragma unroll
      for (int r=0; r<4; r++){
        int x = xt*16 + lq*4 + r;
        int y = yt*16 + lr;
        if (x < SX && y < SY){
          float v = acc2[ii][yt][r];
          s += v; ss += v*v;
        }
      }
    }
  }
  for (int off = 32; off >= 1; off >>= 1){ s += __shfl_down(s,off); ss += __shfl_down(ss,off); }
  if (lane == 0){ sred[0][wv] = s; sred[1][wv] = ss; }
  __syncthreads();
  if (t == 0){
    float S = sred[0][0]+sred[0][1]+sred[0][2]+sred[0][3];
    float SS = sred[1][0]+sred[1][1]+sred[1][2]+sred[1][3];
    float mean = S * (1.0f/IMG);
    float var  = SS * (1.0f/IMG) - mean*mean;
    mb[0] = mean; mb[1] = rsqrtf(var + 1e-5f);
  }
  __syncthreads();
  float mean1 = mb[0], istd1 = mb[1];

  for (int ii=t; ii<8064; ii+=256)
    *(ushort4*)&LB[DAT + ii*4] = make_ushort4(0,0,0,0);
  float s2 = 0.f, ss2 = 0.f;
  #pragma unroll
  for (int ii=0; ii<3; ii++){
    int xt = wv*3 + ii;
    #pragma unroll
    for (int yt=0; yt<9; yt++){
      #pragma unroll
      for (int r=0; r<4; r++){
        int x = xt*16 + lq*4 + r;
        int y = yt*16 + lr;
        float d = 0.f;
        if (x < SX && y < SY){
          d = gelu_f((acc2[ii][yt][r] - mean1) * istd1);
          s2 += d; ss2 += d*d;
        }
        acc2[ii][yt][r] = d;
      }
    }
  }
  for (int off = 32; off >= 1; off >>= 1){ s2 += __shfl_down(s2,off); ss2 += __shfl_down(ss2,off); }
  if (lane == 0){ sred[0][wv] = s2; sred[1][wv] = ss2; }
  __syncthreads();
  if (t == 0){
    float S = sred[0][0]+sred[0][1]+sred[0][2]+sred[0][3];
    float SS = sred[1][0]+sred[1][1]+sred[1][2]+sred[1][3];
    float mean = S * (1.0f/IMG);
    float var  = SS * (1.0f/IMG) - mean*mean;
    mb[0] = mean; mb[1] = rsqrtf(var + 1e-5f);
  }
  __syncthreads();

  #pragma unroll
  for (int ii=0; ii<3; ii++){
    int xt = wv*3 + ii;
    #pragma unroll
    for (int yt=0; yt<9; yt++){
      #pragma unroll
      for (int r=0; r<4; r++){
        int x = xt*16 + lq*4 + r;
        int y = yt*16 + lr;
        if (x < SX && y < SY)
          LB[DAT + x*168 + y] = f2bf(acc2[ii][yt][r]);
      }
    }
  }
  __syncthreads();

  f32x4 accf[2][3] = {};
  #pragma unroll
  for (int ks=0; ks<5; ks++){
    short8 tyh[2], tyl[2];
    #pragma unroll
    for (int mt=0; mt<2; mt++){
      tyh[mt] = ld_g8(&TyH[(mt*16+lr)*168 + ks*32 + lq*8]);
      tyl[mt] = ld_g8(&TyL[(mt*16+lr)*168 + ks*32 + lq*8]);
    }
    #pragma unroll
    for (int j=0; j<3; j++){
      int xr = (wv*3 + j)*16 + lr;
      short8 dh = *(const short8*)&LB[DAT + xr*168 + ks*32 + lq*8];
      #pragma unroll
      for (int mt=0; mt<2; mt++){
        accf[mt][j] = __builtin_amdgcn_mfma_f32_16x16x32_bf16(tyh[mt], dh, accf[mt][j], 0,0,0);
        accf[mt][j] = __builtin_amdgcn_mfma_f32_16x16x32_bf16(tyl[mt], dh, accf[mt][j], 0,0,0);
      }
    }
  }
  __syncthreads();

  {
    float mean2 = mb[0], istd2 = mb[1];
    #pragma unroll
    for (int mt=0; mt<2; mt++){
      #pragma unroll
      for (int j=0; j<3; j++){
        int xr = (wv*3 + j)*16 + lr;
        #pragma unroll
        for (int r=0; r<4; r++){
          int m = mt*16 + lq*4 + r;
          float v = accf[mt][j][r];
          if (m == 0) v -= 130.0f*mean2;
          v *= istd2;
          unsigned short h,l; split_bf(v,h,l);
          LB[YTH + m*200 + xr] = h;
          LB[YTL + m*200 + xr] = l;
        }
      }
    }
  }
  __syncthreads();

  f32x4 accu[2] = {};
  #pragma unroll
  for (int ks=0; ks<6; ks++){
    short8 txh = ld_g8(&TxH[(wv*16+lr)*200 + ks*32 + lq*8]);
    short8 txl = ld_g8(&TxL[(wv*16+lr)*200 + ks*32 + lq*8]);
    #pragma unroll
    for (int mt=0; mt<2; mt++){
      short8 yh = *(const short8*)&LB[YTH + (mt*16+lr)*200 + ks*32 + lq*8];
      short8 yl = *(const short8*)&LB[YTL + (mt*16+lr)*200 + ks*32 + lq*8];
      accu[mt] = __builtin_amdgcn_mfma_f32_16x16x32_bf16(yh, txh, accu[mt], 0,0,0);
      accu[mt] = __builtin_amdgcn_mfma_f32_16x16x32_bf16(yl, txh, accu[mt], 0,0,0);
      accu[mt] = __builtin_amdgcn_mfma_f32_16x16x32_bf16(yh, txl, accu[mt], 0,0,0);
    }
  }
  float* Ub = U2 + (size_t)bid*2048;
  #pragma unroll
  for (int mt=0; mt<2; mt++){
    #pragma unroll
    for (int r=0; r<4; r++){
      int m = mt*16 + lq*4 + r;
      int n = wv*16 + lr;
      Ub[m*64 + n] = accu[mt][r];
    }
  }
}

// ================= layer-2 inv -> Abf (cvt rows [1872,2808) + padA interleaved) =========
__global__ __launch_bounds__(256) void k_inv1(const float* __restrict__ U2,
                                              const float* __restrict__ w1,
                                              const float* __restrict__ w2,
                                              const unsigned short* __restrict__ TxiH,
                                              const unsigned short* __restrict__ TxiL,
                                              const unsigned short* __restrict__ TiyH,
                                              const unsigned short* __restrict__ TiyL,
                                              unsigned short* __restrict__ Abf,
                                              const float* __restrict__ Wsrc,
                                              unsigned short* __restrict__ Wbf){
  int i = blockIdx.x;
  int bid;
  if (i < 3748){
    if ((i & 3) == 3){
      int r = i >> 2;
      if (r < WTHIRD){ cvt_w_row(Wsrc, Wbf, 2*WTHIRD + r); }
      else {
        for (int j = threadIdx.x; j < B_*2; j += 256){
          int b = j >> 1, h = j & 1;
          *(ushort4*)&Abf[(size_t)b*KPAD + FLATK + h*4] = make_ushort4(0,0,0,0);
        }
      }
      return;
    }
    bid = i - (i >> 2);
  } else {
    bid = i - (WTHIRD + 1);
  }
  constexpr int ZFH = 0, ZFL = 2304, GH = 4608, GL = 12288;
  __shared__ unsigned short LB[19968];
  __shared__ float sred[2][4];
  __shared__ float mb[2];
  int t = threadIdx.x, lane = t&63, wv = t>>6, lr = lane&15, lq = lane>>4;
  int b = bid/3, o = bid - b*3;

  #pragma unroll
  for (int pp=0; pp<2; pp++){
    int p = t + pp*256;
    int kxi = p & 31, ky = p >> 5;
    const float* w = (kxi < 16) ? w1 : w2;
    int kxm = kxi & 15;
    float ar = 0.f, ai = 0.f;
    #pragma unroll
    for (int ci=0; ci<3; ci++){
      const float* Ui = U2 + ((size_t)b*3 + ci)*2048;
      float P = Ui[(2*ky  )*64 + 2*kxi  ];
      float Q = Ui[(2*ky  )*64 + 2*kxi+1];
      float R = Ui[(2*ky+1)*64 + 2*kxi  ];
      float S = Ui[(2*ky+1)*64 + 2*kxi+1];
      float zr = P + S, zi = R - Q;
      size_t wo = ((((size_t)ci*3 + o)*16 + kxm)*16 + ky)*2;
      float wr = w[wo], wi = w[wo+1];
      ar += zr*wr - zi*wi;
      ai += zr*wi + zi*wr;
    }
    unsigned short hr,lr_, hi,li, hn,ln;
    split_bf(ar,hr,lr_); split_bf(ai,hi,li); split_bf(-ai,hn,ln);
    LB[ZFH + (2*ky  )*72 + 2*kxi  ] = hr;  LB[ZFL + (2*ky  )*72 + 2*kxi  ] = lr_;
    LB[ZFH + (2*ky  )*72 + 2*kxi+1] = hn;  LB[ZFL + (2*ky  )*72 + 2*kxi+1] = ln;
    LB[ZFH + (2*ky+1)*72 + 2*kxi  ] = hi;  LB[ZFL + (2*ky+1)*72 + 2*kxi  ] = li;
    LB[ZFH + (2*ky+1)*72 + 2*kxi+1] = hr;  LB[ZFL + (2*ky+1)*72 + 2*kxi+1] = lr_;
  }
  __syncthreads();

  f32x4 acc1[2][3] = {};
  #pragma unroll
  for (int ks=0; ks<2; ks++){
    short8 zh[2], zl[2];
    #pragma unroll
    for (int mt=0; mt<2; mt++){
      zh[mt] = *(const short8*)&LB[ZFH + (mt*16+lr)*72 + ks*32 + lq*8];
      zl[mt] = *(const short8*)&LB[ZFL + (mt*16+lr)*72 + ks*32 + lq*8];
    }
    #pragma unroll
    for (int j=0; j<3; j++){
      int x = (wv*3 + j)*16 + lr;
      short8 txh = ld_g8(&TxiH[x*72 + ks*32 + lq*8]);
      short8 txl = ld_g8(&TxiL[x*72 + ks*32 + lq*8]);
      #pragma unroll
      for (int mt=0; mt<2; mt++){
        acc1[mt][j] = __builtin_amdgcn_mfma_f32_16x16x32_bf16(zh[mt], txh, acc1[mt][j], 0,0,0);
        acc1[mt][j] = __builtin_amdgcn_mfma_f32_16x16x32_bf16(zl[mt], txh, acc1[mt][j], 0,0,0);
        acc1[mt][j] = __builtin_amdgcn_mfma_f32_16x16x32_bf16(zh[mt], txl, acc1[mt][j], 0,0,0);
      }
    }
  }
  #pragma unroll
  for (int mt=0; mt<2; mt++){
    #pragma unroll
    for (int j=0; j<3; j++){
      int x = (wv*3 + j)*16 + lr;
      #pragma unroll
      for (int r=0; r<4; r++){
        int m = mt*16 + lq*4 + r;
        unsigned short h,l; split_bf(acc1[mt][j][r], h, l);
        LB[GH + x*40 + m] = h;
        LB[GL + x*40 + m] = l;
      }
    }
  }
  __syncthreads();

  f32x4 acc2[3][9] = {};
  #pragma unroll
  for (int ii=0; ii<3; ii++){
    int x = (wv*3 + ii)*16 + lr;
    short8 gh = *(const short8*)&LB[GH + x*40 + lq*8];
    short8 gl = *(const short8*)&LB[GL + x*40 + lq*8];
    #pragma unroll
    for (int yt=0; yt<9; yt++){
      short8 tyh = ld_g8(&TiyH[(yt*16+lr)*40 + lq*8]);
      short8 tyl = ld_g8(&TiyL[(yt*16+lr)*40 + lq*8]);
      acc2[ii][yt] = __builtin_amdgcn_mfma_f32_16x16x32_bf16(gh, tyh, acc2[ii][yt], 0,0,0);
      acc2[ii][yt] = __builtin_amdgcn_mfma_f32_16x16x32_bf16(gl, tyh, acc2[ii][yt], 0,0,0);
      acc2[ii][yt] = __builtin_amdgcn_mfma_f32_16x16x32_bf16(gh, tyl, acc2[ii][yt], 0,0,0);
    }
  }

  float s = 0.f, ss = 0.f;
  #pragma unroll
  for (int ii=0; ii<3; ii++){
    int xt = wv*3 + ii;
    #pragma unroll
    for (int yt=0; yt<9; yt++){
      #pragma unroll
      for (int r=0; r<4; r++){
        int x = xt*16 + lq*4 + r;
        int y = yt*16 + lr;
        if (x < SX && y < SY){
          float v = acc2[ii][yt][r];
          s += v; ss += v*v;
        }
      }
    }
  }
  for (int off = 32; off >= 1; off >>= 1){ s += __shfl_down(s,off); ss += __shfl_down(ss,off); }
  if (lane == 0){ sred[0][wv] = s; sred[1][wv] = ss; }
  __syncthreads();
  if (t == 0){
    float S = sred[0][0]+sred[0][1]+sred[0][2]+sred[0][3];
    float SS = sred[1][0]+sred[1][1]+sred[1][2]+sred[1][3];
    float mean = S * (1.0f/IMG);
    float var  = SS * (1.0f/IMG) - mean*mean;
    mb[0] = mean; mb[1] = rsqrtf(var + 1e-5f);
  }
  __syncthreads();
  float mean = mb[0], istd = mb[1];

  unsigned short* dst = Abf + (size_t)b*KPAD + (size_t)o*IMG;
  #pragma unroll
  for (int ii=0; ii<3; ii++){
    int xt = wv*3 + ii;
    #pragma unroll
    for (int yt=0; yt<9; yt++){
      #pragma unroll
      for (int r=0; r<4; r++){
        int x = xt*16 + lq*4 + r;
        int y = yt*16 + lr;
        if (x < SX && y < SY){
          float v = (acc2[ii][yt][r] - mean) * istd;
          dst[x*SY + y] = f2bf(gelu_f(v));
        }
      }
    }
  }
}

// ================= big GEMM: 3-slot ring, prefetch distance 2, vmcnt(8), XCD+XOR ======
__global__ __launch_bounds__(256) void k_gemm_fast(const unsigned short* __restrict__ Abf,
                                                   const unsigned short* __restrict__ Wbf,
                                                   float* __restrict__ Cpart){
  __shared__ unsigned short As[3][128*32];   // 24 KB
  __shared__ unsigned short Bs[3][128*32];   // 24 KB
  int t = threadIdx.x;
  int lid = blockIdx.x;
  int xcd = lid & 7, inner = lid >> 3;
  int gq = inner >> 3, bx = inner & 7;
  int g = gq*8 + xcd;
  int by = g >> 2, kz = g & 3;
  int ks0 = kz*KCH, ks1 = min(ks0 + KCH, KSTEPS);
  int ns = ks1 - ks0;
  int lane = t & 63, wv = t >> 6;
  int lr = lane & 15, lq = lane >> 4;
  int wr = wv >> 1, wc = wv & 1;
  int srow = t >> 2;
  int scol = ((t & 3) ^ ((srow >> 1) & 3)) * 8;   // pre-swizzled global source chunk
  const unsigned short* ga0 = Abf + (size_t)(bx*128 + srow)*KPAD + scol;
  const unsigned short* ga1 = ga0 + (size_t)64*KPAD;
  int wrow0 = min(by*128 + srow, HID1-1);
  int wrow1 = min(by*128 + 64 + srow, HID1-1);
  const unsigned short* gb0 = Wbf + (size_t)wrow0*KPAD + scol;
  const unsigned short* gb1 = Wbf + (size_t)wrow1*KPAD + scol;
  int lofs = srow*32 + (t & 3)*8;
  f32x4 acc[4][4] = {};

  // prologue: tiles ks0, ks0+1 -> slots 0,1  (8 loads outstanding)
  {
    size_t gk0 = (size_t)ks0*32;
    gl_lds16(ga0 + gk0, &As[0][lofs]);
    gl_lds16(ga1 + gk0, &As[0][2048 + lofs]);
    gl_lds16(gb0 + gk0, &Bs[0][lofs]);
    gl_lds16(gb1 + gk0, &Bs[0][2048 + lofs]);
    size_t gk1 = (size_t)min(ks0+1, ks1-1)*32;
    gl_lds16(ga0 + gk1, &As[1][lofs]);
    gl_lds16(ga1 + gk1, &As[1][2048 + lofs]);
    gl_lds16(gb0 + gk1, &Bs[1][lofs]);
    gl_lds16(gb1 + gk1, &Bs[1][2048 + lofs]);
  }
  int cur = 0, pf = 2;   // pf = (cur+2)%3 maintained incrementally
  for (int s = 0; s < ns; ++s){
    // issue tile s+2 (clamped; lands in dead slot pf)
    size_t gk = (size_t)min(ks0 + s + 2, ks1 - 1)*32;
    gl_lds16(ga0 + gk, &As[pf][lofs]);
    gl_lds16(ga1 + gk, &As[pf][2048 + lofs]);
    gl_lds16(gb0 + gk, &Bs[pf][lofs]);
    gl_lds16(gb1 + gk, &Bs[pf][2048 + lofs]);
    // 12 outstanding; retire oldest 4 (= tile s); tiles s+1, s+2 stay in flight
    asm volatile("s_waitcnt vmcnt(8)" ::: "memory");
    __builtin_amdgcn_s_barrier();          // all waves: slot cur ready
    const unsigned short* ar = As[cur];
    const unsigned short* br = Bs[cur];
    short8 a[4], b[4];
    #pragma unroll
    for (int m = 0; m < 4; m++){
      int ra = wr*64 + m*16 + lr;
      a[m] = *(const short8*)&ar[ra*32 + (lq ^ ((ra >> 1) & 3))*8];
    }
    #pragma unroll
    for (int n = 0; n < 4; n++){
      int rb = wc*64 + n*16 + lr;
      b[n] = *(const short8*)&br[rb*32 + (lq ^ ((rb >> 1) & 3))*8];
    }
    #pragma unroll
    for (int m = 0; m < 4; m++){
      #pragma unroll
      for (int n = 0; n < 4; n++){
        acc[m][n] = __builtin_amdgcn_mfma_f32_16x16x32_bf16(a[m], b[n], acc[m][n], 0, 0, 0);
      }
    }
    __builtin_amdgcn_s_barrier();          // ds_reads of slot cur done block-wide
    cur = (cur == 2) ? 0 : cur + 1;
    pf  = (pf  == 2) ? 0 : pf  + 1;
  }
  asm volatile("s_waitcnt vmcnt(0)" ::: "memory");   // drain clamped dups before exit

  float* Cp = Cpart + (size_t)kz*B_*H1STR;
  #pragma unroll
  for (int m = 0; m < 4; m++){
    int grow = bx*128 + wr*64 + m*16 + lq*4;
    #pragma unroll
    for (int n = 0; n < 4; n++){
      int gcol = by*128 + wc*64 + n*16 + lr;
      #pragma unroll
      for (int r = 0; r < 4; r++)
        Cp[(size_t)(grow + r)*H1STR + gcol] = acc[m][n][r];
    }
  }
}

// ================= split-K reduce (4-way) + bias + relu =================
__global__ void k_red(const float* __restrict__ Cp, const float* __restrict__ bias,
                      float* __restrict__ h1){
  size_t idx = (size_t)(blockIdx.x*256 + threadIdx.x)*4;
  if (idx >= (size_t)B_*H1STR) return;
  int col = (int)(idx % H1STR);
  float4 acc = make_float4(0.f,0.f,0.f,0.f);
  #pragma unroll
  for (int j = 0; j < NKZ; j++){
    float4 v = *(const float4*)(Cp + (size_t)j*B_*H1STR + idx);
    acc.x += v.x; acc.y += v.y; acc.z += v.z; acc.w += v.w;
  }
  float4 o;
  o.x = fmaxf(acc.x + ((col+0)<HID1 ? bias[col+0] : 0.f), 0.f);
  o.y = fmaxf(acc.y + ((col+1)<HID1 ? bias[col+1] : 0.f), 0.f);
  o.z = fmaxf(acc.z + ((col+2)<HID1 ? bias[col+2] : 0.f), 0.f);
  o.w = fmaxf(acc.w + ((col+3)<HID1 ? bias[col+3] : 0.f), 0.f);
  *(float4*)(h1 + idx) = o;
}

// ================= out1 layer 2 =================
__global__ __launch_bounds__(256) void k_gemm2(const float* __restrict__ h1,
                                               const float* __restrict__ w2,
                                               const float* __restrict__ b2,
                                               float* __restrict__ o1){
  __shared__ float hs[16][68];
  __shared__ float wsm[16][68];
  int t = threadIdx.x;
  int bx = blockIdx.x, by = blockIdx.y;
  int r = t >> 4, c4 = (t & 15) * 4;
  int bi = t >> 4, oi = t & 15;
  float acc = 0.f;
  for (int ks = 0; ks < 44; ks++){
    int gk = ks*64 + c4;
    float4 va = make_float4(0.f,0.f,0.f,0.f);
    if (gk < HID1) va = *(const float4*)&h1[(size_t)(bx*16 + r)*H1STR + gk];
    *(float4*)&hs[r][c4] = va;
    int go = by*16 + r;
    float4 vb = make_float4(0.f,0.f,0.f,0.f);
    if (gk < HID1 && go < NOUT) vb = *(const float4*)&w2[(size_t)go*HID1 + gk];
    *(float4*)&wsm[r][c4] = vb;
    __syncthreads();
    #pragma unroll 8
    for (int k = 0; k < 64; k++) acc += hs[bi][k] * wsm[oi][k];
    __syncthreads();
  }
  int go = by*16 + oi;
  if (go < NOUT) o1[(size_t)(bx*16 + bi)*NOUT + go] = acc + b2[go];
}

// ================= final reg2 MLP =================
__global__ void k_reg2(const float* __restrict__ o1, const float* __restrict__ xin,
                       const float* __restrict__ w1, const float* __restrict__ b1,
                       const float* __restrict__ w2, const float* __restrict__ b2,
                       float* __restrict__ outp){
  __shared__ float s[360];
  __shared__ float tt[180];
  int b = blockIdx.x, t = threadIdx.x;
  if (t < 180){
    s[2*t]   = o1[b*NOUT + t];
    s[2*t+1] = (xin[(size_t)b*SX*XROW + t*XROW + (XROW-1)] - 400.0f) * 0.01f;
  }
  __syncthreads();
  if (t < 180){
    float a = b1[t];
    for (int j = 0; j < 360; j++) a += s[j] * w1[t*360 + j];
    tt[t] = fmaxf(a, 0.0f);
  }
  __syncthreads();
  if (t < 180){
    float a = b2[t];
    for (int j = 0; j < 180; j++) a += tt[j] * w2[t*180 + j];
    outp[b*NOUT + t] = a*100.0f + 400.0f;
  }
}

extern "C" void kernel_launch(void* const* d_in, const int* in_sizes, int n_in,
                              void* d_out, int out_size, void* d_ws, size_t ws_size,
                              hipStream_t stream){
  const float* xin   = (const float*)d_in[0];
  const float* wA0   = (const float*)d_in[1];
  const float* wB0   = (const float*)d_in[2];
  const float* wA1   = (const float*)d_in[3];
  const float* wB1   = (const float*)d_in[4];
  const float* o1w1  = (const float*)d_in[5];
  const float* o1b1  = (const float*)d_in[6];
  const float* o1w2  = (const float*)d_in[7];
  const float* o1b2  = (const float*)d_in[8];
  const float* r2w1  = (const float*)d_in[9];
  const float* r2b1  = (const float*)d_in[10];
  const float* r2w2  = (const float*)d_in[11];
  const float* r2b2  = (const float*)d_in[12];
  float* ws  = (float*)d_ws;
  float* out = (float*)d_out;

  unsigned short* tab = (unsigned short*)ws;
  unsigned short *TyH = tab,            *TyL = tab + TY_SH;
  unsigned short *TxH = TyL + TY_SH,    *TxL = TxH + TX_SH;
  unsigned short *TxiH = TxL + TX_SH,   *TxiL = TxiH + TXI_SH;
  unsigned short *TiyH = TxiL + TXI_SH, *TiyL = TiyH + TIY_SH;

  size_t oU1  = 38400;
  size_t oUg  = oU1  + (size_t)B_*2048;
  size_t oU2  = oUg  + 4096;
  size_t oAbf = oU2  + (size_t)3072*2048;
  size_t oWbf = oAbf + (size_t)B_*KPAD/2;
  size_t oCp  = oWbf + (size_t)HID1*KPAD/2;
  size_t oH1  = oCp  + (size_t)NKZ*B_*H1STR;
  size_t oO1  = oH1  + (size_t)B_*H1STR;

  float *U1 = ws + oU1, *Ug = ws + oUg, *U2 = ws + oU2;
  unsigned short *Abf = (unsigned short*)(ws + oAbf);
  unsigned short *Wbf = (unsigned short*)(ws + oWbf);
  float *Cpart = ws + oCp, *H1 = ws + oH1, *O1 = ws + oO1;

  k_tables2<<<54, 256, 0, stream>>>(TyH, TyL, TxH, TxL, TxiH, TxiL, TiyH, TiyL);

  // layer 1 fwd  (W rows [0,936) interleaved 1:1)
  k_fwd0<<<B_ + 2 + WTHIRD, 256, 0, stream>>>(xin, TyH, TyL, TxH, TxL, U1, Ug, o1w1, Wbf);
  // layer-1 inv fused with layer-2 fwd  (W rows [936,1872) interleaved 3:1)
  k_mid<<<3072 + WTHIRD, 256, 0, stream>>>(U1, Ug, wA0, wB0, TxiH, TxiL, TiyH, TiyL,
                                           TyH, TyL, TxH, TxL, U2, o1w1, Wbf);
  // layer-2 inv -> Abf  (W rows [1872,2808) + padA interleaved 3:1)
  k_inv1<<<3072 + WTHIRD + 1, 256, 0, stream>>>(U2, wA1, wB1, TxiH, TxiL, TiyH, TiyL,
                                                Abf, o1w1, Wbf);

  // head
  k_gemm_fast<<<704, 256, 0, stream>>>(Abf, Wbf, Cpart);
  k_red<<<(B_*H1STR/4 + 255)/256, 256, 0, stream>>>(Cpart, o1b1, H1);
  k_gemm2<<<dim3(64, 12), 256, 0, stream>>>(H1, o1w2, o1b2, O1);
  k_reg2<<<B_, 192, 0, stream>>>(O1, xin, r2w1, r2b1, r2w2, r2b2, out);
}

// Round 15
// 1199.494 us; speedup vs baseline: 1.1355x; 1.1355x over previous
//
#include <hip/hip_runtime.h>
#include <hip/hip_bf16.h>
#include <math.h>

#ifndef M_PI
#define M_PI 3.14159265358979323846
#endif

#define B_    1024
#define SX    180
#define SY    130
#define NC    3
#define IMG   23400
#define FLATK 70200
#define KPAD  70208
#define HID1  2808
#define NOUT  180
#define XROW  131
#define H1STR 2816
#define KSTEPS 2194   // KPAD/32
#define KCH    549    // ceil(KSTEPS/4)
#define NKZ    4
#define WTHIRD 936    // HID1/3 W-rows converted per spectral kernel

typedef __attribute__((ext_vector_type(8))) short short8;
typedef __attribute__((ext_vector_type(4))) float f32x4;
typedef __attribute__((address_space(3))) unsigned int lds_u32;
typedef __attribute__((address_space(1))) const unsigned int glb_u32;

// table sizes (shorts), padded so fragment reads stay in-bounds
#define TY_SH   5632
#define TX_SH   12800
#define TXI_SH  13824
#define TIY_SH  6144

__device__ __forceinline__ unsigned short f2bf(float f){
  __hip_bfloat16 h = __float2bfloat16(f);
  return __builtin_bit_cast(unsigned short, h);
}
__device__ __forceinline__ float bf2f(unsigned short u){
  __hip_bfloat16 h = __builtin_bit_cast(__hip_bfloat16, u);
  return __bfloat162float(h);
}
__device__ __forceinline__ void split_bf(float f, unsigned short &hi, unsigned short &lo){
  hi = f2bf(f);
  lo = f2bf(f - bf2f(hi));
}
__device__ __forceinline__ void gl_lds16(const void* g, void* l){
  __builtin_amdgcn_global_load_lds((glb_u32*)g, (lds_u32*)l, 16, 0, 0);
}
__device__ __forceinline__ float gelu_f(float v){
  return 0.5f * v * (1.0f + erff(v * 0.70710678118654752f));
}
__device__ __forceinline__ short8 ld_g8(const unsigned short* p){
  return *(const short8*)p;
}

// ---- W-row fp32->bf16 convert (one row per block; coalesced) ----
__device__ __forceinline__ void cvt_w_row(const float* __restrict__ W,
                                          unsigned short* __restrict__ Wbf, int row){
  int t = threadIdx.x;
  const float* src = W + (size_t)row*FLATK;
  unsigned short* dst = Wbf + (size_t)row*KPAD;
  for (int gi = t; gi < KPAD/8; gi += 256){
    if (gi*8 >= FLATK){
      *(ushort4*)(dst + gi*8)     = make_ushort4(0,0,0,0);
      *(ushort4*)(dst + gi*8 + 4) = make_ushort4(0,0,0,0);
    } else {
      float4 v0 = *(const float4*)(src + gi*8);
      float4 v1 = *(const float4*)(src + gi*8 + 4);
      ushort4 u0, u1;
      u0.x=f2bf(v0.x); u0.y=f2bf(v0.y); u0.z=f2bf(v0.z); u0.w=f2bf(v0.w);
      u1.x=f2bf(v1.x); u1.y=f2bf(v1.y); u1.z=f2bf(v1.z); u1.w=f2bf(v1.w);
      *(ushort4*)(dst + gi*8)     = u0;
      *(ushort4*)(dst + gi*8 + 4) = u1;
    }
  }
}

// ================= tables (split hi/lo bf16, padded) =================
__global__ void k_tables2(unsigned short* __restrict__ TyH, unsigned short* __restrict__ TyL,
                          unsigned short* __restrict__ TxH, unsigned short* __restrict__ TxL,
                          unsigned short* __restrict__ TxiH, unsigned short* __restrict__ TxiL,
                          unsigned short* __restrict__ TiyH, unsigned short* __restrict__ TiyL){
  int i = blockIdx.x*256 + threadIdx.x;
  unsigned short h, l;
  if (i < TY_SH){
    int m = i/168, y = i%168;
    float v = 0.f;
    if (m < 32 && y < SY){
      int ky = m>>1, ri = m&1;
      double ang = 2.0*M_PI*(double)((ky*y)%SY)/(double)SY;
      v = ri ? (float)(-sin(ang)) : (float)cos(ang);
    }
    split_bf(v,h,l); TyH[i]=h; TyL[i]=l;
  }
  if (i < TX_SH){
    int n = i/200, x = i%200;
    float v = 0.f;
    if (x < SX){
      int kxi = n>>1, ri = n&1;
      int kx = (kxi<16)? kxi : kxi+148;
      double ang = 2.0*M_PI*(double)((kx*x)%SX)/(double)SX;
      v = ri ? (float)sin(ang) : (float)cos(ang);
    }
    split_bf(v,h,l); TxH[i]=h; TxL[i]=l;
  }
  if (i < TXI_SH){
    int x = i/72, k = i%72;
    float v = 0.f;
    if (x < SX && k < 64){
      int kxi = k>>1, ri = k&1;
      int kx = (kxi<16)? kxi : kxi+148;
      double ang = 2.0*M_PI*(double)((kx*x)%SX)/(double)SX;
      v = (float)((ri ? sin(ang) : cos(ang)) / (double)SX);
    }
    split_bf(v,h,l); TxiH[i]=h; TxiL[i]=l;
  }
  if (i < TIY_SH){
    int y = i/40, m = i%40;
    float v = 0.f;
    if (y < SY && m < 32){
      int ky = m>>1, ri = m&1;
      if (m == 0) v = 1.0f/(float)SY;
      else if (m == 1) v = 0.f;
      else {
        double ang = 2.0*M_PI*(double)((ky*y)%SY)/(double)SY;
        v = (float)((ri ? -2.0*sin(ang) : 2.0*cos(ang)) / (double)SY);
      }
    }
    split_bf(v,h,l); TiyH[i]=h; TiyL[i]=l;
  }
}

// ================= layer-1 fwd (cvt rows [0,936) interleaved 1:1) =================
__global__ __launch_bounds__(256) void k_fwd0(const float* __restrict__ xin,
                                              const unsigned short* __restrict__ TyH,
                                              const unsigned short* __restrict__ TyL,
                                              const unsigned short* __restrict__ TxH,
                                              const unsigned short* __restrict__ TxL,
                                              float* __restrict__ U1,
                                              float* __restrict__ Ug,
                                              const float* __restrict__ Wsrc,
                                              unsigned short* __restrict__ Wbf){
  int i = blockIdx.x;
  int bid;
  if (i < 1872){
    if (i & 1){ cvt_w_row(Wsrc, Wbf, i >> 1); return; }
    bid = i >> 1;
  } else {
    bid = i - WTHIRD;
  }
  constexpr int DHI = 0;
  constexpr int YTH = 0, YTL = 6400;
  __shared__ unsigned short LB[32256];
  __shared__ float sred[2][4];
  __shared__ float mb[2];
  int t = threadIdx.x, lane = t&63, wv = t>>6, lr = lane&15, lq = lane>>4;

  float s = 0.f, ss = 0.f;
  for (int ii=t; ii<7680; ii+=256){
    int row = ii/40, c4 = (ii - row*40)*4;
    float v[4];
    #pragma unroll
    for (int j=0;j<4;j++){
      int y = c4 + j;
      float val = 0.f;
      if (row < SX && y < SY){
        if (bid < B_)       val = xin[(size_t)bid*(SX*XROW) + row*XROW + y];
        else if (bid == B_) val = (float)row * (1.0f/179.0f);
        else                val = (float)y * (1.0f/129.0f);
      }
      s += val; ss += val*val;
      v[j] = val;
    }
    ushort4 u; u.x=f2bf(v[0]); u.y=f2bf(v[1]); u.z=f2bf(v[2]); u.w=f2bf(v[3]);
    *(ushort4*)&LB[DHI + row*168 + c4] = u;
  }
  for (int o = 32; o >= 1; o >>= 1){ s += __shfl_down(s,o); ss += __shfl_down(ss,o); }
  if (lane == 0){ sred[0][wv] = s; sred[1][wv] = ss; }
  __syncthreads();
  if (t == 0){
    float S = sred[0][0]+sred[0][1]+sred[0][2]+sred[0][3];
    float SS = sred[1][0]+sred[1][1]+sred[1][2]+sred[1][3];
    float mean = S * (1.0f/IMG);
    float var  = SS * (1.0f/IMG) - mean*mean;
    mb[0] = mean; mb[1] = rsqrtf(var + 1e-5f);
  }
  __syncthreads();

  f32x4 acc[2][3] = {};
  #pragma unroll
  for (int ks=0; ks<5; ks++){
    short8 tyh[2], tyl[2];
    #pragma unroll
    for (int mt=0; mt<2; mt++){
      tyh[mt] = ld_g8(&TyH[(mt*16+lr)*168 + ks*32 + lq*8]);
      tyl[mt] = ld_g8(&TyL[(mt*16+lr)*168 + ks*32 + lq*8]);
    }
    #pragma unroll
    for (int j=0; j<3; j++){
      int xr = (wv*3 + j)*16 + lr;
      short8 dh = *(const short8*)&LB[DHI + xr*168 + ks*32 + lq*8];
      #pragma unroll
      for (int mt=0; mt<2; mt++){
        acc[mt][j] = __builtin_amdgcn_mfma_f32_16x16x32_bf16(tyh[mt], dh, acc[mt][j], 0,0,0);
        acc[mt][j] = __builtin_amdgcn_mfma_f32_16x16x32_bf16(tyl[mt], dh, acc[mt][j], 0,0,0);
      }
    }
  }
  __syncthreads();

  {
    float mean = mb[0], istd = mb[1];
    #pragma unroll
    for (int mt=0; mt<2; mt++){
      #pragma unroll
      for (int j=0; j<3; j++){
        int xr = (wv*3 + j)*16 + lr;
        #pragma unroll
        for (int r=0; r<4; r++){
          int m = mt*16 + lq*4 + r;
          float v = acc[mt][j][r];
          if (m == 0) v -= 130.0f*mean;
          v *= istd;
          unsigned short h,l; split_bf(v,h,l);
          LB[YTH + m*200 + xr] = h;
          LB[YTL + m*200 + xr] = l;
        }
      }
    }
  }
  __syncthreads();

  f32x4 acc2[2] = {};
  #pragma unroll
  for (int ks=0; ks<6; ks++){
    short8 txh = ld_g8(&TxH[(wv*16+lr)*200 + ks*32 + lq*8]);
    short8 txl = ld_g8(&TxL[(wv*16+lr)*200 + ks*32 + lq*8]);
    #pragma unroll
    for (int mt=0; mt<2; mt++){
      short8 yh = *(const short8*)&LB[YTH + (mt*16+lr)*200 + ks*32 + lq*8];
      short8 yl = *(const short8*)&LB[YTL + (mt*16+lr)*200 + ks*32 + lq*8];
      acc2[mt] = __builtin_amdgcn_mfma_f32_16x16x32_bf16(yh, txh, acc2[mt], 0,0,0);
      acc2[mt] = __builtin_amdgcn_mfma_f32_16x16x32_bf16(yl, txh, acc2[mt], 0,0,0);
      acc2[mt] = __builtin_amdgcn_mfma_f32_16x16x32_bf16(yh, txl, acc2[mt], 0,0,0);
    }
  }
  float* Ub = (bid < B_) ? (U1 + (size_t)bid*2048) : (Ug + (size_t)(bid - B_)*2048);
  #pragma unroll
  for (int mt=0; mt<2; mt++){
    #pragma unroll
    for (int r=0; r<4; r++){
      int m = mt*16 + lq*4 + r;
      int n = wv*16 + lr;
      Ub[m*64 + n] = acc2[mt][r];
    }
  }
}

// ================= k_mid (cvt rows [936,1872) interleaved 3:1) =================
__global__ __launch_bounds__(256) void k_mid(const float* __restrict__ U1,
                                             const float* __restrict__ Ug,
                                             const float* __restrict__ w1,
                                             const float* __restrict__ w2,
                                             const unsigned short* __restrict__ TxiH,
                                             const unsigned short* __restrict__ TxiL,
                                             const unsigned short* __restrict__ TiyH,
                                             const unsigned short* __restrict__ TiyL,
                                             const unsigned short* __restrict__ TyH,
                                             const unsigned short* __restrict__ TyL,
                                             const unsigned short* __restrict__ TxH,
                                             const unsigned short* __restrict__ TxL,
                                             float* __restrict__ U2,
                                             const float* __restrict__ Wsrc,
                                             unsigned short* __restrict__ Wbf){
  int i = blockIdx.x;
  int bid;
  if (i < 3744){
    if ((i & 3) == 3){ cvt_w_row(Wsrc, Wbf, WTHIRD + (i >> 2)); return; }
    bid = i - (i >> 2);
  } else {
    bid = i - WTHIRD;
  }
  constexpr int ZFH = 0, ZFL = 2304, GH = 4608, GL = 12288;
  constexpr int DAT = 0;
  constexpr int YTH = 0, YTL = 6400;
  __shared__ unsigned short LB[32256];
  __shared__ float sred[2][4];
  __shared__ float mb[2];
  int t = threadIdx.x, lane = t&63, wv = t>>6, lr = lane&15, lq = lane>>4;
  int b = bid/3, o = bid - b*3;

  #pragma unroll
  for (int pp=0; pp<2; pp++){
    int p = t + pp*256;
    int kxi = p & 31, ky = p >> 5;
    const float* w = (kxi < 16) ? w1 : w2;
    int kxm = kxi & 15;
    float ar = 0.f, ai = 0.f;
    #pragma unroll
    for (int ci=0; ci<3; ci++){
      const float* Ui = (ci==0) ? (U1 + (size_t)b*2048) : (Ug + (size_t)(ci-1)*2048);
      float P = Ui[(2*ky  )*64 + 2*kxi  ];
      float Q = Ui[(2*ky  )*64 + 2*kxi+1];
      float R = Ui[(2*ky+1)*64 + 2*kxi  ];
      float S = Ui[(2*ky+1)*64 + 2*kxi+1];
      float zr = P + S, zi = R - Q;
      size_t wo = ((((size_t)ci*3 + o)*16 + kxm)*16 + ky)*2;
      float wr = w[wo], wi = w[wo+1];
      ar += zr*wr - zi*wi;
      ai += zr*wi + zi*wr;
    }
    unsigned short hr,lr_, hi,li, hn,ln;
    split_bf(ar,hr,lr_); split_bf(ai,hi,li); split_bf(-ai,hn,ln);
    LB[ZFH + (2*ky  )*72 + 2*kxi  ] = hr;  LB[ZFL + (2*ky  )*72 + 2*kxi  ] = lr_;
    LB[ZFH + (2*ky  )*72 + 2*kxi+1] = hn;  LB[ZFL + (2*ky  )*72 + 2*kxi+1] = ln;
    LB[ZFH + (2*ky+1)*72 + 2*kxi  ] = hi;  LB[ZFL + (2*ky+1)*72 + 2*kxi  ] = li;
    LB[ZFH + (2*ky+1)*72 + 2*kxi+1] = hr;  LB[ZFL + (2*ky+1)*72 + 2*kxi+1] = lr_;
  }
  __syncthreads();

  f32x4 acc1[2][3] = {};
  #pragma unroll
  for (int ks=0; ks<2; ks++){
    short8 zh[2], zl[2];
    #pragma unroll
    for (int mt=0; mt<2; mt++){
      zh[mt] = *(const short8*)&LB[ZFH + (mt*16+lr)*72 + ks*32 + lq*8];
      zl[mt] = *(const short8*)&LB[ZFL + (mt*16+lr)*72 + ks*32 + lq*8];
    }
    #pragma unroll
    for (int j=0; j<3; j++){
      int x = (wv*3 + j)*16 + lr;
      short8 txh = ld_g8(&TxiH[x*72 + ks*32 + lq*8]);
      short8 txl = ld_g8(&TxiL[x*72 + ks*32 + lq*8]);
      #pragma unroll
      for (int mt=0; mt<2; mt++){
        acc1[mt][j] = __builtin_amdgcn_mfma_f32_16x16x32_bf16(zh[mt], txh, acc1[mt][j], 0,0,0);
        acc1[mt][j] = __builtin_amdgcn_mfma_f32_16x16x32_bf16(zl[mt], txh, acc1[mt][j], 0,0,0);
        acc1[mt][j] = __builtin_amdgcn_mfma_f32_16x16x32_bf16(zh[mt], txl, acc1[mt][j], 0,0,0);
      }
    }
  }
  #pragma unroll
  for (int mt=0; mt<2; mt++){
    #pragma unroll
    for (int j=0; j<3; j++){
      int x = (wv*3 + j)*16 + lr;
      #pragma unroll
      for (int r=0; r<4; r++){
        int m = mt*16 + lq*4 + r;
        unsigned short h,l; split_bf(acc1[mt][j][r], h, l);
        LB[GH + x*40 + m] = h;
        LB[GL + x*40 + m] = l;
      }
    }
  }
  __syncthreads();

  f32x4 acc2[3][9] = {};
  #pragma unroll
  for (int ii=0; ii<3; ii++){
    int x = (wv*3 + ii)*16 + lr;
    short8 gh = *(const short8*)&LB[GH + x*40 + lq*8];
    short8 gl = *(const short8*)&LB[GL + x*40 + lq*8];
    #pragma unroll
    for (int yt=0; yt<9; yt++){
      short8 tyh = ld_g8(&TiyH[(yt*16+lr)*40 + lq*8]);
      short8 tyl = ld_g8(&TiyL[(yt*16+lr)*40 + lq*8]);
      acc2[ii][yt] = __builtin_amdgcn_mfma_f32_16x16x32_bf16(gh, tyh, acc2[ii][yt], 0,0,0);
      acc2[ii][yt] = __builtin_amdgcn_mfma_f32_16x16x32_bf16(gl, tyh, acc2[ii][yt], 0,0,0);
      acc2[ii][yt] = __builtin_amdgcn_mfma_f32_16x16x32_bf16(gh, tyl, acc2[ii][yt], 0,0,0);
    }
  }

  float s = 0.f, ss = 0.f;
  #pragma unroll
  for (int ii=0; ii<3; ii++){
    int xt = wv*3 + ii;
    #pragma unroll
    for (int yt=0; yt<9; yt++){
      #pragma unroll
      for (int r=0; r<4; r++){
        int x = xt*16 + lq*4 + r;
        int y = yt*16 + lr;
        if (x < SX && y < SY){
          float v = acc2[ii][yt][r];
          s += v; ss += v*v;
        }
      }
    }
  }
  for (int off = 32; off >= 1; off >>= 1){ s += __shfl_down(s,off); ss += __shfl_down(ss,off); }
  if (lane == 0){ sred[0][wv] = s; sred[1][wv] = ss; }
  __syncthreads();
  if (t == 0){
    float S = sred[0][0]+sred[0][1]+sred[0][2]+sred[0][3];
    float SS = sred[1][0]+sred[1][1]+sred[1][2]+sred[1][3];
    float mean = S * (1.0f/IMG);
    float var  = SS * (1.0f/IMG) - mean*mean;
    mb[0] = mean; mb[1] = rsqrtf(var + 1e-5f);
  }
  __syncthreads();
  float mean1 = mb[0], istd1 = mb[1];

  for (int ii=t; ii<8064; ii+=256)
    *(ushort4*)&LB[DAT + ii*4] = make_ushort4(0,0,0,0);
  float s2 = 0.f, ss2 = 0.f;
  #pragma unroll
  for (int ii=0; ii<3; ii++){
    int xt = wv*3 + ii;
    #pragma unroll
    for (int yt=0; yt<9; yt++){
      #pragma unroll
      for (int r=0; r<4; r++){
        int x = xt*16 + lq*4 + r;
        int y = yt*16 + lr;
        float d = 0.f;
        if (x < SX && y < SY){
          d = gelu_f((acc2[ii][yt][r] - mean1) * istd1);
          s2 += d; ss2 += d*d;
        }
        acc2[ii][yt][r] = d;
      }
    }
  }
  for (int off = 32; off >= 1; off >>= 1){ s2 += __shfl_down(s2,off); ss2 += __shfl_down(ss2,off); }
  if (lane == 0){ sred[0][wv] = s2; sred[1][wv] = ss2; }
  __syncthreads();
  if (t == 0){
    float S = sred[0][0]+sred[0][1]+sred[0][2]+sred[0][3];
    float SS = sred[1][0]+sred[1][1]+sred[1][2]+sred[1][3];
    float mean = S * (1.0f/IMG);
    float var  = SS * (1.0f/IMG) - mean*mean;
    mb[0] = mean; mb[1] = rsqrtf(var + 1e-5f);
  }
  __syncthreads();

  #pragma unroll
  for (int ii=0; ii<3; ii++){
    int xt = wv*3 + ii;
    #pragma unroll
    for (int yt=0; yt<9; yt++){
      #pragma unroll
      for (int r=0; r<4; r++){
        int x = xt*16 + lq*4 + r;
        int y = yt*16 + lr;
        if (x < SX && y < SY)
          LB[DAT + x*168 + y] = f2bf(acc2[ii][yt][r]);
      }
    }
  }
  __syncthreads();

  f32x4 accf[2][3] = {};
  #pragma unroll
  for (int ks=0; ks<5; ks++){
    short8 tyh[2], tyl[2];
    #pragma unroll
    for (int mt=0; mt<2; mt++){
      tyh[mt] = ld_g8(&TyH[(mt*16+lr)*168 + ks*32 + lq*8]);
      tyl[mt] = ld_g8(&TyL[(mt*16+lr)*168 + ks*32 + lq*8]);
    }
    #pragma unroll
    for (int j=0; j<3; j++){
      int xr = (wv*3 + j)*16 + lr;
      short8 dh = *(const short8*)&LB[DAT + xr*168 + ks*32 + lq*8];
      #pragma unroll
      for (int mt=0; mt<2; mt++){
        accf[mt][j] = __builtin_amdgcn_mfma_f32_16x16x32_bf16(tyh[mt], dh, accf[mt][j], 0,0,0);
        accf[mt][j] = __builtin_amdgcn_mfma_f32_16x16x32_bf16(tyl[mt], dh, accf[mt][j], 0,0,0);
      }
    }
  }
  __syncthreads();

  {
    float mean2 = mb[0], istd2 = mb[1];
    #pragma unroll
    for (int mt=0; mt<2; mt++){
      #pragma unroll
      for (int j=0; j<3; j++){
        int xr = (wv*3 + j)*16 + lr;
        #pragma unroll
        for (int r=0; r<4; r++){
          int m = mt*16 + lq*4 + r;
          float v = accf[mt][j][r];
          if (m == 0) v -= 130.0f*mean2;
          v *= istd2;
          unsigned short h,l; split_bf(v,h,l);
          LB[YTH + m*200 + xr] = h;
          LB[YTL + m*200 + xr] = l;
        }
      }
    }
  }
  __syncthreads();

  f32x4 accu[2] = {};
  #pragma unroll
  for (int ks=0; ks<6; ks++){
    short8 txh = ld_g8(&TxH[(wv*16+lr)*200 + ks*32 + lq*8]);
    short8 txl = ld_g8(&TxL[(wv*16+lr)*200 + ks*32 + lq*8]);
    #pragma unroll
    for (int mt=0; mt<2; mt++){
      short8 yh = *(const short8*)&LB[YTH + (mt*16+lr)*200 + ks*32 + lq*8];
      short8 yl = *(const short8*)&LB[YTL + (mt*16+lr)*200 + ks*32 + lq*8];
      accu[mt] = __builtin_amdgcn_mfma_f32_16x16x32_bf16(yh, txh, accu[mt], 0,0,0);
      accu[mt] = __builtin_amdgcn_mfma_f32_16x16x32_bf16(yl, txh, accu[mt], 0,0,0);
      accu[mt] = __builtin_amdgcn_mfma_f32_16x16x32_bf16(yh, txl, accu[mt], 0,0,0);
    }
  }
  float* Ub = U2 + (size_t)bid*2048;
  #pragma unroll
  for (int mt=0; mt<2; mt++){
    #pragma unroll
    for (int r=0; r<4; r++){
      int m = mt*16 + lq*4 + r;
      int n = wv*16 + lr;
      Ub[m*64 + n] = accu[mt][r];
    }
  }
}

// ================= layer-2 inv -> Abf (cvt rows [1872,2808) + padA interleaved) =========
__global__ __launch_bounds__(256) void k_inv1(const float* __restrict__ U2,
                                              const float* __restrict__ w1,
                                              const float* __restrict__ w2,
                                              const unsigned short* __restrict__ TxiH,
                                              const unsigned short* __restrict__ TxiL,
                                              const unsigned short* __restrict__ TiyH,
                                              const unsigned short* __restrict__ TiyL,
                                              unsigned short* __restrict__ Abf,
                                              const float* __restrict__ Wsrc,
                                              unsigned short* __restrict__ Wbf){
  int i = blockIdx.x;
  int bid;
  if (i < 3748){
    if ((i & 3) == 3){
      int r = i >> 2;
      if (r < WTHIRD){ cvt_w_row(Wsrc, Wbf, 2*WTHIRD + r); }
      else {
        for (int j = threadIdx.x; j < B_*2; j += 256){
          int b = j >> 1, h = j & 1;
          *(ushort4*)&Abf[(size_t)b*KPAD + FLATK + h*4] = make_ushort4(0,0,0,0);
        }
      }
      return;
    }
    bid = i - (i >> 2);
  } else {
    bid = i - (WTHIRD + 1);
  }
  constexpr int ZFH = 0, ZFL = 2304, GH = 4608, GL = 12288;
  __shared__ unsigned short LB[19968];
  __shared__ float sred[2][4];
  __shared__ float mb[2];
  int t = threadIdx.x, lane = t&63, wv = t>>6, lr = lane&15, lq = lane>>4;
  int b = bid/3, o = bid - b*3;

  #pragma unroll
  for (int pp=0; pp<2; pp++){
    int p = t + pp*256;
    int kxi = p & 31, ky = p >> 5;
    const float* w = (kxi < 16) ? w1 : w2;
    int kxm = kxi & 15;
    float ar = 0.f, ai = 0.f;
    #pragma unroll
    for (int ci=0; ci<3; ci++){
      const float* Ui = U2 + ((size_t)b*3 + ci)*2048;
      float P = Ui[(2*ky  )*64 + 2*kxi  ];
      float Q = Ui[(2*ky  )*64 + 2*kxi+1];
      float R = Ui[(2*ky+1)*64 + 2*kxi  ];
      float S = Ui[(2*ky+1)*64 + 2*kxi+1];
      float zr = P + S, zi = R - Q;
      size_t wo = ((((size_t)ci*3 + o)*16 + kxm)*16 + ky)*2;
      float wr = w[wo], wi = w[wo+1];
      ar += zr*wr - zi*wi;
      ai += zr*wi + zi*wr;
    }
    unsigned short hr,lr_, hi,li, hn,ln;
    split_bf(ar,hr,lr_); split_bf(ai,hi,li); split_bf(-ai,hn,ln);
    LB[ZFH + (2*ky  )*72 + 2*kxi  ] = hr;  LB[ZFL + (2*ky  )*72 + 2*kxi  ] = lr_;
    LB[ZFH + (2*ky  )*72 + 2*kxi+1] = hn;  LB[ZFL + (2*ky  )*72 + 2*kxi+1] = ln;
    LB[ZFH + (2*ky+1)*72 + 2*kxi  ] = hi;  LB[ZFL + (2*ky+1)*72 + 2*kxi  ] = li;
    LB[ZFH + (2*ky+1)*72 + 2*kxi+1] = hr;  LB[ZFL + (2*ky+1)*72 + 2*kxi+1] = lr_;
  }
  __syncthreads();

  f32x4 acc1[2][3] = {};
  #pragma unroll
  for (int ks=0; ks<2; ks++){
    short8 zh[2], zl[2];
    #pragma unroll
    for (int mt=0; mt<2; mt++){
      zh[mt] = *(const short8*)&LB[ZFH + (mt*16+lr)*72 + ks*32 + lq*8];
      zl[mt] = *(const short8*)&LB[ZFL + (mt*16+lr)*72 + ks*32 + lq*8];
    }
    #pragma unroll
    for (int j=0; j<3; j++){
      int x = (wv*3 + j)*16 + lr;
      short8 txh = ld_g8(&TxiH[x*72 + ks*32 + lq*8]);
      short8 txl = ld_g8(&TxiL[x*72 + ks*32 + lq*8]);
      #pragma unroll
      for (int mt=0; mt<2; mt++){
        acc1[mt][j] = __builtin_amdgcn_mfma_f32_16x16x32_bf16(zh[mt], txh, acc1[mt][j], 0,0,0);
        acc1[mt][j] = __builtin_amdgcn_mfma_f32_16x16x32_bf16(zl[mt], txh, acc1[mt][j], 0,0,0);
        acc1[mt][j] = __builtin_amdgcn_mfma_f32_16x16x32_bf16(zh[mt], txl, acc1[mt][j], 0,0,0);
      }
    }
  }
  #pragma unroll
  for (int mt=0; mt<2; mt++){
    #pragma unroll
    for (int j=0; j<3; j++){
      int x = (wv*3 + j)*16 + lr;
      #pragma unroll
      for (int r=0; r<4; r++){
        int m = mt*16 + lq*4 + r;
        unsigned short h,l; split_bf(acc1[mt][j][r], h, l);
        LB[GH + x*40 + m] = h;
        LB[GL + x*40 + m] = l;
      }
    }
  }
  __syncthreads();

  f32x4 acc2[3][9] = {};
  #pragma unroll
  for (int ii=0; ii<3; ii++){
    int x = (wv*3 + ii)*16 + lr;
    short8 gh = *(const short8*)&LB[GH + x*40 + lq*8];
    short8 gl = *(const short8*)&LB[GL + x*40 + lq*8];
    #pragma unroll
    for (int yt=0; yt<9; yt++){
      short8 tyh = ld_g8(&TiyH[(yt*16+lr)*40 + lq*8]);
      short8 tyl = ld_g8(&TiyL[(yt*16+lr)*40 + lq*8]);
      acc2[ii][yt] = __builtin_amdgcn_mfma_f32_16x16x32_bf16(gh, tyh, acc2[ii][yt], 0,0,0);
      acc2[ii][yt] = __builtin_amdgcn_mfma_f32_16x16x32_bf16(gl, tyh, acc2[ii][yt], 0,0,0);
      acc2[ii][yt] = __builtin_amdgcn_mfma_f32_16x16x32_bf16(gh, tyl, acc2[ii][yt], 0,0,0);
    }
  }

  float s = 0.f, ss = 0.f;
  #pragma unroll
  for (int ii=0; ii<3; ii++){
    int xt = wv*3 + ii;
    #pragma unroll
    for (int yt=0; yt<9; yt++){
      #pragma unroll
      for (int r=0; r<4; r++){
        int x = xt*16 + lq*4 + r;
        int y = yt*16 + lr;
        if (x < SX && y < SY){
          float v = acc2[ii][yt][r];
          s += v; ss += v*v;
        }
      }
    }
  }
  for (int off = 32; off >= 1; off >>= 1){ s += __shfl_down(s,off); ss += __shfl_down(ss,off); }
  if (lane == 0){ sred[0][wv] = s; sred[1][wv] = ss; }
  __syncthreads();
  if (t == 0){
    float S = sred[0][0]+sred[0][1]+sred[0][2]+sred[0][3];
    float SS = sred[1][0]+sred[1][1]+sred[1][2]+sred[1][3];
    float mean = S * (1.0f/IMG);
    float var  = SS * (1.0f/IMG) - mean*mean;
    mb[0] = mean; mb[1] = rsqrtf(var + 1e-5f);
  }
  __syncthreads();
  float mean = mb[0], istd = mb[1];

  unsigned short* dst = Abf + (size_t)b*KPAD + (size_t)o*IMG;
  #pragma unroll
  for (int ii=0; ii<3; ii++){
    int xt = wv*3 + ii;
    #pragma unroll
    for (int yt=0; yt<9; yt++){
      #pragma unroll
      for (int r=0; r<4; r++){
        int x = xt*16 + lq*4 + r;
        int y = yt*16 + lr;
        if (x < SX && y < SY){
          float v = (acc2[ii][yt][r] - mean) * istd;
          dst[x*SY + y] = f2bf(gelu_f(v));
        }
      }
    }
  }
}

// ================= big GEMM (round-12/13 proven): dbuf + vmcnt(4) + XCD + XOR, kz=4 ======
__global__ __launch_bounds__(256) void k_gemm_fast(const unsigned short* __restrict__ Abf,
                                                   const unsigned short* __restrict__ Wbf,
                                                   float* __restrict__ Cpart){
  __shared__ unsigned short As[2][128*32];
  __shared__ unsigned short Bs[2][128*32];
  int t = threadIdx.x;
  int lid = blockIdx.x;
  int xcd = lid & 7, inner = lid >> 3;
  int gq = inner >> 3, bx = inner & 7;
  int g = gq*8 + xcd;
  int by = g >> 2, kz = g & 3;
  int ks0 = kz*KCH, ks1 = min(ks0 + KCH, KSTEPS);
  int lane = t & 63, wv = t >> 6;
  int lr = lane & 15, lq = lane >> 4;
  int wr = wv >> 1, wc = wv & 1;
  int srow = t >> 2;
  int scol = ((t & 3) ^ ((srow >> 1) & 3)) * 8;
  const unsigned short* ga0 = Abf + (size_t)(bx*128 + srow)*KPAD + scol;
  const unsigned short* ga1 = ga0 + (size_t)64*KPAD;
  int wrow0 = min(by*128 + srow, HID1-1);
  int wrow1 = min(by*128 + 64 + srow, HID1-1);
  const unsigned short* gb0 = Wbf + (size_t)wrow0*KPAD + scol;
  const unsigned short* gb1 = Wbf + (size_t)wrow1*KPAD + scol;
  int lofs = srow*32 + (t & 3)*8;
  f32x4 acc[4][4] = {};

  {
    size_t gk = (size_t)ks0*32;
    gl_lds16(ga0 + gk, &As[0][lofs]);
    gl_lds16(ga1 + gk, &As[0][2048 + lofs]);
    gl_lds16(gb0 + gk, &Bs[0][lofs]);
    gl_lds16(gb1 + gk, &Bs[0][2048 + lofs]);
  }
  int cur = 0;
  for (int ks = ks0; ks < ks1; ks++){
    if (ks + 1 < ks1){
      size_t gk = (size_t)(ks+1)*32;
      int nb = cur ^ 1;
      gl_lds16(ga0 + gk, &As[nb][lofs]);
      gl_lds16(ga1 + gk, &As[nb][2048 + lofs]);
      gl_lds16(gb0 + gk, &Bs[nb][lofs]);
      gl_lds16(gb1 + gk, &Bs[nb][2048 + lofs]);
      asm volatile("s_waitcnt vmcnt(4)" ::: "memory");
    } else {
      asm volatile("s_waitcnt vmcnt(0)" ::: "memory");
    }
    __builtin_amdgcn_s_barrier();
    short8 a[4], b[4];
    #pragma unroll
    for (int m = 0; m < 4; m++){
      int ra = wr*64 + m*16 + lr;
      a[m] = *(const short8*)&As[cur][ra*32 + (lq ^ ((ra >> 1) & 3))*8];
    }
    #pragma unroll
    for (int n = 0; n < 4; n++){
      int rb = wc*64 + n*16 + lr;
      b[n] = *(const short8*)&Bs[cur][rb*32 + (lq ^ ((rb >> 1) & 3))*8];
    }
    #pragma unroll
    for (int m = 0; m < 4; m++){
      #pragma unroll
      for (int n = 0; n < 4; n++){
        acc[m][n] = __builtin_amdgcn_mfma_f32_16x16x32_bf16(a[m], b[n], acc[m][n], 0, 0, 0);
      }
    }
    __builtin_amdgcn_s_barrier();
    cur ^= 1;
  }
  float* Cp = Cpart + (size_t)kz*B_*H1STR;
  #pragma unroll
  for (int m = 0; m < 4; m++){
    int grow = bx*128 + wr*64 + m*16 + lq*4;
    #pragma unroll
    for (int n = 0; n < 4; n++){
      int gcol = by*128 + wc*64 + n*16 + lr;
      #pragma unroll
      for (int r = 0; r < 4; r++)
        Cp[(size_t)(grow + r)*H1STR + gcol] = acc[m][n][r];
    }
  }
}

// ================= split-K reduce (4-way) + bias + relu =================
__global__ void k_red(const float* __restrict__ Cp, const float* __restrict__ bias,
                      float* __restrict__ h1){
  size_t idx = (size_t)(blockIdx.x*256 + threadIdx.x)*4;
  if (idx >= (size_t)B_*H1STR) return;
  int col = (int)(idx % H1STR);
  float4 acc = make_float4(0.f,0.f,0.f,0.f);
  #pragma unroll
  for (int j = 0; j < NKZ; j++){
    float4 v = *(const float4*)(Cp + (size_t)j*B_*H1STR + idx);
    acc.x += v.x; acc.y += v.y; acc.z += v.z; acc.w += v.w;
  }
  float4 o;
  o.x = fmaxf(acc.x + ((col+0)<HID1 ? bias[col+0] : 0.f), 0.f);
  o.y = fmaxf(acc.y + ((col+1)<HID1 ? bias[col+1] : 0.f), 0.f);
  o.z = fmaxf(acc.z + ((col+2)<HID1 ? bias[col+2] : 0.f), 0.f);
  o.w = fmaxf(acc.w + ((col+3)<HID1 ? bias[col+3] : 0.f), 0.f);
  *(float4*)(h1 + idx) = o;
}

// ================= out1 layer 2 =================
__global__ __launch_bounds__(256) void k_gemm2(const float* __restrict__ h1,
                                               const float* __restrict__ w2,
                                               const float* __restrict__ b2,
                                               float* __restrict__ o1){
  __shared__ float hs[16][68];
  __shared__ float wsm[16][68];
  int t = threadIdx.x;
  int bx = blockIdx.x, by = blockIdx.y;
  int r = t >> 4, c4 = (t & 15) * 4;
  int bi = t >> 4, oi = t & 15;
  float acc = 0.f;
  for (int ks = 0; ks < 44; ks++){
    int gk = ks*64 + c4;
    float4 va = make_float4(0.f,0.f,0.f,0.f);
    if (gk < HID1) va = *(const float4*)&h1[(size_t)(bx*16 + r)*H1STR + gk];
    *(float4*)&hs[r][c4] = va;
    int go = by*16 + r;
    float4 vb = make_float4(0.f,0.f,0.f,0.f);
    if (gk < HID1 && go < NOUT) vb = *(const float4*)&w2[(size_t)go*HID1 + gk];
    *(float4*)&wsm[r][c4] = vb;
    __syncthreads();
    #pragma unroll 8
    for (int k = 0; k < 64; k++) acc += hs[bi][k] * wsm[oi][k];
    __syncthreads();
  }
  int go = by*16 + oi;
  if (go < NOUT) o1[(size_t)(bx*16 + bi)*NOUT + go] = acc + b2[go];
}

// ================= final reg2 MLP =================
__global__ void k_reg2(const float* __restrict__ o1, const float* __restrict__ xin,
                       const float* __restrict__ w1, const float* __restrict__ b1,
                       const float* __restrict__ w2, const float* __restrict__ b2,
                       float* __restrict__ outp){
  __shared__ float s[360];
  __shared__ float tt[180];
  int b = blockIdx.x, t = threadIdx.x;
  if (t < 180){
    s[2*t]   = o1[b*NOUT + t];
    s[2*t+1] = (xin[(size_t)b*SX*XROW + t*XROW + (XROW-1)] - 400.0f) * 0.01f;
  }
  __syncthreads();
  if (t < 180){
    float a = b1[t];
    for (int j = 0; j < 360; j++) a += s[j] * w1[t*360 + j];
    tt[t] = fmaxf(a, 0.0f);
  }
  __syncthreads();
  if (t < 180){
    float a = b2[t];
    for (int j = 0; j < 180; j++) a += tt[j] * w2[t*180 + j];
    outp[b*NOUT + t] = a*100.0f + 400.0f;
  }
}

extern "C" void kernel_launch(void* const* d_in, const int* in_sizes, int n_in,
                              void* d_out, int out_size, void* d_ws, size_t ws_size,
                              hipStream_t stream){
  const float* xin   = (const float*)d_in[0];
  const float* wA0   = (const float*)d_in[1];
  const float* wB0   = (const float*)d_in[2];
  const float* wA1   = (const float*)d_in[3];
  const float* wB1   = (const float*)d_in[4];
  const float* o1w1  = (const float*)d_in[5];
  const float* o1b1  = (const float*)d_in[6];
  const float* o1w2  = (const float*)d_in[7];
  const float* o1b2  = (const float*)d_in[8];
  const float* r2w1  = (const float*)d_in[9];
  const float* r2b1  = (const float*)d_in[10];
  const float* r2w2  = (const float*)d_in[11];
  const float* r2b2  = (const float*)d_in[12];
  float* ws  = (float*)d_ws;
  float* out = (float*)d_out;

  unsigned short* tab = (unsigned short*)ws;
  unsigned short *TyH = tab,            *TyL = tab + TY_SH;
  unsigned short *TxH = TyL + TY_SH,    *TxL = TxH + TX_SH;
  unsigned short *TxiH = TxL + TX_SH,   *TxiL = TxiH + TXI_SH;
  unsigned short *TiyH = TxiL + TXI_SH, *TiyL = TiyH + TIY_SH;

  size_t oU1  = 38400;
  size_t oUg  = oU1  + (size_t)B_*2048;
  size_t oU2  = oUg  + 4096;
  size_t oAbf = oU2  + (size_t)3072*2048;
  size_t oWbf = oAbf + (size_t)B_*KPAD/2;
  size_t oCp  = oWbf + (size_t)HID1*KPAD/2;
  size_t oH1  = oCp  + (size_t)NKZ*B_*H1STR;
  size_t oO1  = oH1  + (size_t)B_*H1STR;

  float *U1 = ws + oU1, *Ug = ws + oUg, *U2 = ws + oU2;
  unsigned short *Abf = (unsigned short*)(ws + oAbf);
  unsigned short *Wbf = (unsigned short*)(ws + oWbf);
  float *Cpart = ws + oCp, *H1 = ws + oH1, *O1 = ws + oO1;

  k_tables2<<<54, 256, 0, stream>>>(TyH, TyL, TxH, TxL, TxiH, TxiL, TiyH, TiyL);

  // layer 1 fwd  (W rows [0,936) interleaved 1:1)
  k_fwd0<<<B_ + 2 + WTHIRD, 256, 0, stream>>>(xin, TyH, TyL, TxH, TxL, U1, Ug, o1w1, Wbf);
  // layer-1 inv fused with layer-2 fwd  (W rows [936,1872) interleaved 3:1)
  k_mid<<<3072 + WTHIRD, 256, 0, stream>>>(U1, Ug, wA0, wB0, TxiH, TxiL, TiyH, TiyL,
                                           TyH, TyL, TxH, TxL, U2, o1w1, Wbf);
  // layer-2 inv -> Abf  (W rows [1872,2808) + padA interleaved 3:1)
  k_inv1<<<3072 + WTHIRD + 1, 256, 0, stream>>>(U2, wA1, wB1, TxiH, TxiL, TiyH, TiyL,
                                                Abf, o1w1, Wbf);

  // head
  k_gemm_fast<<<704, 256, 0, stream>>>(Abf, Wbf, Cpart);
  k_red<<<(B_*H1STR/4 + 255)/256, 256, 0, stream>>>(Cpart, o1b1, H1);
  k_gemm2<<<dim3(64, 12), 256, 0, stream>>>(H1, o1w2, o1b2, O1);
  k_reg2<<<B_, 192, 0, stream>>>(O1, xin, r2w1, r2b1, r2w2, r2b2, out);
}